// Round 9
// baseline (209.282 us; speedup 1.0000x reference)
//
#include <hip/hip_runtime.h>
#include <hip/hip_bf16.h>
#include <math.h>

#define N_POINTS 32
#define SPACE_DIM 16
#define EMB 512
#define THRESH 0.1f
#define MAX_ITER 10
#define KDIM 256   // K fixed by the problem (feat=256)

// log2-domain constants
#define NEG10LOG2E -14.42695040888963f   // -10*log2(e): C -> Crow2
#define EPS_LN2     0.0693147180559945f  // eps*ln2
#define LOGMU2     -4.99999953834f       // log2(1/32 + 1e-8)

typedef _Float16 half8 __attribute__((ext_vector_type(8)));
typedef _Float16 half4 __attribute__((ext_vector_type(4)));
typedef float floatx4 __attribute__((ext_vector_type(4)));

#define BSTRIDE 264   // halves; 528 B rows -> b128-aligned, 2-way max (free)

// ---------------- GEMM v2: Z = X @ W, N-tile=256, X-in-reg, dbuf W ---------
// (R7-proven; also zeroes the 9 election counters for sinkhorn's merged tail)
__global__ __launch_bounds__(256) void gemm_fused(
    const float* __restrict__ X, const float* __restrict__ W,
    float* __restrict__ Z, int M, int K, int N, unsigned* __restrict__ counter)
{
    (void)K;  // == KDIM by problem construction
    if (blockIdx.x == 0 && blockIdx.y == 0 && threadIdx.x < 9)
        counter[threadIdx.x] = 0u;

    __shared__ _Float16 Bs[2][64][BSTRIDE];   // 2 x 33.8 KB

    int t = threadIdx.x;
    int wave = t >> 6;
    int lane = t & 63;
    int quad = lane >> 4;
    int l16 = lane & 15;
    int n_base = blockIdx.y * 256;

    // ---- load + convert this lane's X slice ONCE (8 kk x 8 floats) ----
    int mrow = blockIdx.x * 64 + wave * 16 + l16;
    int msafe = mrow < M ? mrow : M - 1;
    const float4* xp = (const float4*)(X + (size_t)msafe * KDIM);

    half8 ah[8];
    #pragma unroll
    for (int kk = 0; kk < 8; ++kk) {
        float4 lo = xp[kk * 8 + quad * 2];
        float4 hi = xp[kk * 8 + quad * 2 + 1];
        ah[kk] = (half8){(_Float16)lo.x, (_Float16)lo.y, (_Float16)lo.z, (_Float16)lo.w,
                         (_Float16)hi.x, (_Float16)hi.y, (_Float16)hi.z, (_Float16)hi.w};
    }

    // ---- W subtile staging: [256k x 64n] fp32 -> Bs[buf][n][k] f16 ----
    auto stage = [&](int buf, int ct2) {
        int n0 = n_base + ct2 * 64;
        #pragma unroll
        for (int s = 0; s < 4; ++s) {
            int u = s * 256 + t;
            int nb = u & 15;          // n-group (4 cols)
            int kb = u >> 4;          // k-group (4 rows)
            float4 r0v = *(const float4*)&W[(size_t)(kb * 4 + 0) * N + n0 + nb * 4];
            float4 r1v = *(const float4*)&W[(size_t)(kb * 4 + 1) * N + n0 + nb * 4];
            float4 r2v = *(const float4*)&W[(size_t)(kb * 4 + 2) * N + n0 + nb * 4];
            float4 r3v = *(const float4*)&W[(size_t)(kb * 4 + 3) * N + n0 + nb * 4];
            float c0[4] = {r0v.x, r0v.y, r0v.z, r0v.w};
            float c1[4] = {r1v.x, r1v.y, r1v.z, r1v.w};
            float c2[4] = {r2v.x, r2v.y, r2v.z, r2v.w};
            float c3[4] = {r3v.x, r3v.y, r3v.z, r3v.w};
            #pragma unroll
            for (int c = 0; c < 4; ++c) {
                half4 h = {(_Float16)c0[c], (_Float16)c1[c],
                           (_Float16)c2[c], (_Float16)c3[c]};
                *(half4*)&Bs[buf][nb * 4 + c][kb * 4] = h;
            }
        }
    };

    stage(0, 0);

    int rbase = blockIdx.x * 64 + wave * 16 + quad * 4;

    #pragma unroll
    for (int ct2 = 0; ct2 < 4; ++ct2) {
        __syncthreads();                       // buf[ct2&1] staged & prior reads done
        if (ct2 < 3) stage((ct2 + 1) & 1, ct2 + 1);   // overlap next stage w/ MFMA

        int cur = ct2 & 1;
        floatx4 acc[4] = {{0.f,0.f,0.f,0.f},{0.f,0.f,0.f,0.f},
                          {0.f,0.f,0.f,0.f},{0.f,0.f,0.f,0.f}};
        #pragma unroll
        for (int kk = 0; kk < 8; ++kk) {
            #pragma unroll
            for (int ct = 0; ct < 4; ++ct) {
                half8 b = *(const half8*)&Bs[cur][ct * 16 + l16][kk * 32 + quad * 8];
                acc[ct] = __builtin_amdgcn_mfma_f32_16x16x32_f16(ah[kk], b, acc[ct], 0, 0, 0);
            }
        }

        #pragma unroll
        for (int ct = 0; ct < 4; ++ct) {
            int col = n_base + ct2 * 64 + ct * 16 + l16;
            #pragma unroll
            for (int r = 0; r < 4; ++r) {
                int row = rbase + r;
                if (row < M) Z[(size_t)row * N + col] = acc[ct][r];
            }
        }
    }
}

// ---------------- Fused Sinkhorn + merged finalize (2-level election) -------
// Main body = R6's verified 53us kernel. The tail merges R6's finalize via a
// CHEAP hierarchical election: 8 group counters (256 arrivals each, separate
// cache lines, arrivals amortized over block-finish skew) + 1 super counter
// (8 arrivals). This avoids R5's failure mode (2048 ACQ_REL RMWs on ONE line
// ~25-70us). Tail body = R6's ILP finalize (proven ~4us). launch_bounds
// stays (256,4): R2's (256,8) spilled everything.
#define WPB 4

__global__ __launch_bounds__(256, 4) void sinkhorn_fused(
    const float* __restrict__ Z,
    const int* __restrict__ ep, const int* __restrict__ en,
    int nE,
    float* __restrict__ cost_all,   // [MAX_ITER][2nE]
    float* __restrict__ err_part,   // [MAX_ITER][gridDim.x]
    unsigned* __restrict__ counter, // [9]: 8 group + 1 super
    float* __restrict__ out)
{
    __shared__ float shm[WPB][32 * 36];  // union: sb=32x20, csh=32x36; tail scratch
    __shared__ float uvs[WPB][64];       // U2[0:32], V2[32:64]; then err publish

    int tid = threadIdx.x;
    int wv = tid >> 6;
    int t = tid & 63;
    int b = blockIdx.x * WPB + wv;

    int side = (b >= nE) ? 1 : 0;   // uniform per block (nE % WPB == 0)
    int e = b - side * nE;
    const int* edges = side ? en : ep;
    int nx = edges[e];
    int ny = edges[e + nE];

    int c = t & 31;
    int h = t >> 5;
    int r0 = h * 16;

    float* sb  = shm[wv];
    float* csh = shm[wv];
    float* Ul  = uvs[wv];
    float* Vl  = uvs[wv] + 32;

    // stage b point rows into LDS, padded stride 20
    {
        const float4* zb4 = (const float4*)(Z + (size_t)ny * EMB);
        float4 q0 = zb4[t * 2];
        float4 q1 = zb4[t * 2 + 1];
        float* dst = sb + (t >> 1) * 20 + (t & 1) * 8;
        ((float4*)dst)[0] = q0;
        ((float4*)dst)[1] = q1;
    }
    // own a-row in registers
    float areg[16];
    {
        const float4* za4 = (const float4*)(Z + (size_t)nx * EMB + c * SPACE_DIM);
        float4 a0 = za4[0], a1 = za4[1], a2 = za4[2], a3 = za4[3];
        areg[0]=a0.x; areg[1]=a0.y; areg[2]=a0.z; areg[3]=a0.w;
        areg[4]=a1.x; areg[5]=a1.y; areg[6]=a1.z; areg[7]=a1.w;
        areg[8]=a2.x; areg[9]=a2.y; areg[10]=a2.z; areg[11]=a2.w;
        areg[12]=a3.x; areg[13]=a3.y; areg[14]=a3.z; areg[15]=a3.w;
    }

    // Crow[jj] = -10*log2e * ||a_c - b_{r0+jj}||^2
    float Crow[16];
    #pragma unroll
    for (int jj = 0; jj < 16; ++jj) {
        const float* bp = sb + (r0 + jj) * 20;
        float s = 0.f;
        #pragma unroll
        for (int d = 0; d < SPACE_DIM; ++d) {
            float diff = areg[d] - bp[d];
            s = fmaf(diff, diff, s);
        }
        Crow[jj] = s * NEG10LOG2E;
    }
    // transpose through LDS (stride 36) to get column fragment
    #pragma unroll
    for (int g = 0; g < 4; ++g) {
        *(float4*)&csh[c * 36 + r0 + g * 4] =
            make_float4(Crow[g*4+0], Crow[g*4+1], Crow[g*4+2], Crow[g*4+3]);
    }
    float Ccol[16];
    #pragma unroll
    for (int ii = 0; ii < 16; ++ii)
        Ccol[ii] = csh[(r0 + ii) * 36 + c];

    Vl[c] = 0.f;
    float U = 0.f;
    float ccp[MAX_ITER];   // per-lane cost partials (state after iter k+1)
    float dup[MAX_ITER];   // per-lane du of iter k (duplicated across halves)

    #pragma unroll        // FULL unroll: ccp/dup indices static -> VGPRs
    for (int it = 0; it < MAX_ITER; ++it) {
        // ---- row pass ----
        float w[16];
        {
            const float4* vp = (const float4*)(Vl + r0);
            float4 v0 = vp[0], v1 = vp[1], v2 = vp[2], v3 = vp[3];
            float vv[16] = {v0.x,v0.y,v0.z,v0.w, v1.x,v1.y,v1.z,v1.w,
                            v2.x,v2.y,v2.z,v2.w, v3.x,v3.y,v3.z,v3.w};
            #pragma unroll
            for (int jj = 0; jj < 16; ++jj) w[jj] = Crow[jj] + vv[jj];
        }
        // pairwise max tree
        float m8[8];
        #pragma unroll
        for (int k = 0; k < 8; ++k) m8[k] = fmaxf(w[k], w[k + 8]);
        float m4a = fmaxf(m8[0], m8[4]), m4b = fmaxf(m8[1], m8[5]);
        float m4c = fmaxf(m8[2], m8[6]), m4d = fmaxf(m8[3], m8[7]);
        float mx = fmaxf(fmaxf(m4a, m4b), fmaxf(m4c, m4d));
        mx = fmaxf(mx, __shfl_xor(mx, 32));

        float ex[16];
        #pragma unroll
        for (int jj = 0; jj < 16; ++jj) ex[jj] = __builtin_amdgcn_exp2f(w[jj] - mx);
        // pairwise sum trees for sm and pc
        float s8[8], p8[8];
        #pragma unroll
        for (int k = 0; k < 8; ++k) {
            s8[k] = ex[k] + ex[k + 8];
            p8[k] = fmaf(ex[k], Crow[k], ex[k + 8] * Crow[k + 8]);
        }
        float sm = ((s8[0]+s8[4]) + (s8[1]+s8[5])) + ((s8[2]+s8[6]) + (s8[3]+s8[7]));
        float pc = ((p8[0]+p8[4]) + (p8[1]+p8[5])) + ((p8[2]+p8[6]) + (p8[3]+p8[7]));
        sm += __shfl_xor(sm, 32);

        // per-lane cost partial of state after `it` iterations (pre-update U)
        if (it > 0) ccp[it - 1] = __builtin_amdgcn_exp2f(U + mx) * pc;

        float Un = LOGMU2 - (mx + __builtin_amdgcn_logf(sm));
        dup[it] = fabsf(Un - U);   // identical in both halves
        U = Un;
        Ul[c] = U;

        // ---- col pass ----
        float wc[16];
        {
            const float4* up = (const float4*)(Ul + r0);
            float4 u0 = up[0], u1 = up[1], u2 = up[2], u3 = up[3];
            float uu[16] = {u0.x,u0.y,u0.z,u0.w, u1.x,u1.y,u1.z,u1.w,
                            u2.x,u2.y,u2.z,u2.w, u3.x,u3.y,u3.z,u3.w};
            #pragma unroll
            for (int ii = 0; ii < 16; ++ii) wc[ii] = Ccol[ii] + uu[ii];
        }
        float n8[8];
        #pragma unroll
        for (int k = 0; k < 8; ++k) n8[k] = fmaxf(wc[k], wc[k + 8]);
        float n4a = fmaxf(n8[0], n8[4]), n4b = fmaxf(n8[1], n8[5]);
        float n4c = fmaxf(n8[2], n8[6]), n4d = fmaxf(n8[3], n8[7]);
        float mx2 = fmaxf(fmaxf(n4a, n4b), fmaxf(n4c, n4d));
        mx2 = fmaxf(mx2, __shfl_xor(mx2, 32));

        float e2[16];
        #pragma unroll
        for (int ii = 0; ii < 16; ++ii) e2[ii] = __builtin_amdgcn_exp2f(wc[ii] - mx2);
        float t8[8];
        #pragma unroll
        for (int k = 0; k < 8; ++k) t8[k] = e2[k] + e2[k + 8];
        float sm2 = ((t8[0]+t8[4]) + (t8[1]+t8[5])) + ((t8[2]+t8[6]) + (t8[3]+t8[7]));
        sm2 += __shfl_xor(sm2, 32);
        float Vn = LOGMU2 - (mx2 + __builtin_amdgcn_logf(sm2));
        Vl[c] = Vn;
    }

    // final-state cost partial -> ccp[MAX_ITER-1]
    {
        const float4* vp = (const float4*)(Vl + r0);
        float4 v0 = vp[0], v1 = vp[1], v2 = vp[2], v3 = vp[3];
        float vv[16] = {v0.x,v0.y,v0.z,v0.w, v1.x,v1.y,v1.z,v1.w,
                        v2.x,v2.y,v2.z,v2.w, v3.x,v3.y,v3.z,v3.w};
        float cc = 0.f;
        #pragma unroll
        for (int jj = 0; jj < 16; ++jj)
            cc = fmaf(__builtin_amdgcn_exp2f(U + Crow[jj] + vv[jj]), Crow[jj], cc);
        ccp[MAX_ITER - 1] = cc;
    }

    // post-loop: 20 independent butterfly chains, latencies overlap
    #pragma unroll
    for (int m = 1; m < 32; m <<= 1) {
        #pragma unroll
        for (int k = 0; k < MAX_ITER; ++k) {
            dup[k] += __shfl_xor(dup[k], m);
            ccp[k] += __shfl_xor(ccp[k], m);
        }
    }
    #pragma unroll
    for (int k = 0; k < MAX_ITER; ++k) ccp[k] += __shfl_xor(ccp[k], 32);

    if (t == 0) {
        #pragma unroll
        for (int k = 0; k < MAX_ITER; ++k)
            cost_all[(size_t)k * (2 * nE) + b] = -EPS_LN2 * ccp[k];
        // publish this wave's err values for the block-combine
        #pragma unroll
        for (int k = 0; k < MAX_ITER; ++k) uvs[wv][k] = dup[k];
    }
    __syncthreads();

    // block-combine err across the 4 waves -> 10 plain f32 stores, no atomics
    if (tid < MAX_ITER) {
        float s4 = uvs[0][tid] + uvs[1][tid] + uvs[2][tid] + uvs[3][tid];
        err_part[(size_t)tid * gridDim.x + blockIdx.x] = EPS_LN2 * s4;
    }

    // ============== 2-level completion election + merged finalize ==========
    // Scratch overlays shm[0] (dead): em_s[96..115], isl[128], loss[200..203]
    float* sred = &shm[0][0];
    float* em_s = sred + 96;
    int*   isl  = (int*)(sred + 128);

    __syncthreads();   // all waves' global stores issued before the fence
    if (tid == 0) {
        __threadfence();                      // release our stores
        int g = (int)(blockIdx.x >> 8);       // 8 groups of 256 blocks
        int last = 0;
        unsigned o1 = __hip_atomic_fetch_add(&counter[g], 1u,
                          __ATOMIC_ACQ_REL, __HIP_MEMORY_SCOPE_AGENT);
        if (o1 == 255u) {
            unsigned o2 = __hip_atomic_fetch_add(&counter[8], 1u,
                              __ATOMIC_ACQ_REL, __HIP_MEMORY_SCOPE_AGENT);
            last = (o2 == 7u);
        }
        *isl = last;
    }
    __syncthreads();
    if (!*isl) return;
    __threadfence();   // acquire side for all threads of the last block

    int nB = (int)gridDim.x;   // 2048

    // ---- Phase A: err row sums (R6 finalize, ILP 8-deep) ----
    for (int r = wv; r < MAX_ITER; r += 4) {
        const float4* p4 = (const float4*)(err_part + (size_t)r * nB);
        float4 v0 = p4[t       ], v1 = p4[t +  64], v2 = p4[t + 128], v3 = p4[t + 192];
        float4 v4 = p4[t + 256], v5 = p4[t + 320], v6 = p4[t + 384], v7 = p4[t + 448];
        float ps = ((v0.x+v0.y)+(v0.z+v0.w)) + ((v1.x+v1.y)+(v1.z+v1.w))
                 + ((v2.x+v2.y)+(v2.z+v2.w)) + ((v3.x+v3.y)+(v3.z+v3.w));
        float ns = ((v4.x+v4.y)+(v4.z+v4.w)) + ((v5.x+v5.y)+(v5.z+v5.w))
                 + ((v6.x+v6.y)+(v6.z+v6.w)) + ((v7.x+v7.y)+(v7.z+v7.w));
        #pragma unroll
        for (int m = 1; m < 64; m <<= 1) {
            ps += __shfl_xor(ps, m);
            ns += __shfl_xor(ns, m);
        }
        if (t == 0) {
            em_s[r] = ps / (float)nE;
            em_s[MAX_ITER + r] = ns / (float)nE;
        }
    }
    __syncthreads();

    int Tp = MAX_ITER, Tn = MAX_ITER;
    for (int i = 0; i < MAX_ITER; ++i)
        if (em_s[i] < THRESH) { Tp = i + 1; break; }
    for (int i = 0; i < MAX_ITER; ++i)
        if (em_s[MAX_ITER + i] < THRESH) { Tn = i + 1; break; }

    // ---- Phase B: final loss (R6 finalize, 8 loads in flight) ----
    const float4* cp4 = (const float4*)(cost_all + (size_t)(Tp - 1) * (2 * nE));
    const float4* cn4 = (const float4*)(cost_all + (size_t)(Tn - 1) * (2 * nE) + nE);
    float4 p0 = cp4[tid      ], p1 = cp4[tid + 256],
           p2 = cp4[tid + 512], p3 = cp4[tid + 768];
    float4 n0 = cn4[tid      ], n1 = cn4[tid + 256],
           n2 = cn4[tid + 512], n3 = cn4[tid + 768];
    float aP = 0.f;
    aP = fmaf(p0.x,p0.x,aP); aP = fmaf(p0.y,p0.y,aP);
    aP = fmaf(p0.z,p0.z,aP); aP = fmaf(p0.w,p0.w,aP);
    aP = fmaf(p1.x,p1.x,aP); aP = fmaf(p1.y,p1.y,aP);
    aP = fmaf(p1.z,p1.z,aP); aP = fmaf(p1.w,p1.w,aP);
    aP = fmaf(p2.x,p2.x,aP); aP = fmaf(p2.y,p2.y,aP);
    aP = fmaf(p2.z,p2.z,aP); aP = fmaf(p2.w,p2.w,aP);
    aP = fmaf(p3.x,p3.x,aP); aP = fmaf(p3.y,p3.y,aP);
    aP = fmaf(p3.z,p3.z,aP); aP = fmaf(p3.w,p3.w,aP);
    float aN = 0.f;
    aN += expf(-n0.x) + expf(-n0.y) + expf(-n0.z) + expf(-n0.w);
    aN += expf(-n1.x) + expf(-n1.y) + expf(-n1.z) + expf(-n1.w);
    aN += expf(-n2.x) + expf(-n2.y) + expf(-n2.z) + expf(-n2.w);
    aN += expf(-n3.x) + expf(-n3.y) + expf(-n3.z) + expf(-n3.w);
    float acc = aP + aN;
    #pragma unroll
    for (int m = 1; m < 64; m <<= 1) acc += __shfl_xor(acc, m);
    if (t == 0) sred[200 + wv] = acc;
    __syncthreads();
    if (tid == 0)
        out[0] = ((sred[200] + sred[201]) + (sred[202] + sred[203])) / (float)nE;
}

extern "C" void kernel_launch(void* const* d_in, const int* in_sizes, int n_in,
                              void* d_out, int out_size, void* d_ws, size_t ws_size,
                              hipStream_t stream)
{
    const float* X = (const float*)d_in[0];
    const float* W = (const float*)d_in[1];
    const int* ep = (const int*)d_in[2];
    const int* en = (const int*)d_in[3];
    float* out = (float*)d_out;

    int K = in_sizes[1] / EMB;     // 256
    int M = in_sizes[0] / K;       // 10000
    int nE = in_sizes[2] / 2;      // 4096

    float* ws = (float*)d_ws;
    float* Z = ws;                                          // M*EMB f32
    float* cost_all = Z + (size_t)M * EMB;                  // MAX_ITER*2nE f32
    float* err_part = cost_all + (size_t)MAX_ITER * 2 * nE; // MAX_ITER*2048 f32
    unsigned* counter = (unsigned*)(err_part + (size_t)MAX_ITER * 2048); // 9 u32

    dim3 gg((M + 63) / 64, 2);
    gemm_fused<<<gg, 256, 0, stream>>>(X, W, Z, M, K, EMB, counter);

    int nblk = (2 * nE) / WPB;   // 2048
    sinkhorn_fused<<<nblk, 64 * WPB, 0, stream>>>(Z, ep, en, nE, cost_all,
                                                  err_part, counter, out);
}

// Round 10
// 208.771 us; speedup vs baseline: 1.0024x; 1.0024x over previous
//
#include <hip/hip_runtime.h>
#include <hip/hip_bf16.h>
#include <math.h>

#define N_POINTS 32
#define SPACE_DIM 16
#define EMB 512
#define THRESH 0.1f
#define MAX_ITER 10
#define KDIM 256   // K fixed by the problem (feat=256)

// log2-domain constants
#define NEG10LOG2E -14.42695040888963f   // -10*log2(e): C -> Crow2
#define EPS_LN2     0.0693147180559945f  // eps*ln2
#define LOGMU2     -4.99999953834f       // log2(1/32 + 1e-8)

// counters padded to one 256-B cache line each (R9 lesson: 9 contiguous u32
// = ONE line -> all 2048 RMWs serialized on a single bouncing line, +97us)
#define CTR_STRIDE 64   // u32s per counter slot (256 B)

typedef _Float16 half8 __attribute__((ext_vector_type(8)));
typedef _Float16 half4 __attribute__((ext_vector_type(4)));
typedef float floatx4 __attribute__((ext_vector_type(4)));

#define BSTRIDE 264   // halves; 528 B rows -> b128-aligned, 2-way max (free)

// ---------------- GEMM v2: Z = X @ W, N-tile=256, X-in-reg, dbuf W ---------
// (R7-proven; also zeroes the 9 padded election counters)
__global__ __launch_bounds__(256) void gemm_fused(
    const float* __restrict__ X, const float* __restrict__ W,
    float* __restrict__ Z, int M, int K, int N, unsigned* __restrict__ counter)
{
    (void)K;  // == KDIM by problem construction
    if (blockIdx.x == 0 && blockIdx.y == 0 && threadIdx.x < 9)
        counter[threadIdx.x * CTR_STRIDE] = 0u;

    __shared__ _Float16 Bs[2][64][BSTRIDE];   // 2 x 33.8 KB

    int t = threadIdx.x;
    int wave = t >> 6;
    int lane = t & 63;
    int quad = lane >> 4;
    int l16 = lane & 15;
    int n_base = blockIdx.y * 256;

    // ---- load + convert this lane's X slice ONCE (8 kk x 8 floats) ----
    int mrow = blockIdx.x * 64 + wave * 16 + l16;
    int msafe = mrow < M ? mrow : M - 1;
    const float4* xp = (const float4*)(X + (size_t)msafe * KDIM);

    half8 ah[8];
    #pragma unroll
    for (int kk = 0; kk < 8; ++kk) {
        float4 lo = xp[kk * 8 + quad * 2];
        float4 hi = xp[kk * 8 + quad * 2 + 1];
        ah[kk] = (half8){(_Float16)lo.x, (_Float16)lo.y, (_Float16)lo.z, (_Float16)lo.w,
                         (_Float16)hi.x, (_Float16)hi.y, (_Float16)hi.z, (_Float16)hi.w};
    }

    // ---- W subtile staging: [256k x 64n] fp32 -> Bs[buf][n][k] f16 ----
    auto stage = [&](int buf, int ct2) {
        int n0 = n_base + ct2 * 64;
        #pragma unroll
        for (int s = 0; s < 4; ++s) {
            int u = s * 256 + t;
            int nb = u & 15;          // n-group (4 cols)
            int kb = u >> 4;          // k-group (4 rows)
            float4 r0v = *(const float4*)&W[(size_t)(kb * 4 + 0) * N + n0 + nb * 4];
            float4 r1v = *(const float4*)&W[(size_t)(kb * 4 + 1) * N + n0 + nb * 4];
            float4 r2v = *(const float4*)&W[(size_t)(kb * 4 + 2) * N + n0 + nb * 4];
            float4 r3v = *(const float4*)&W[(size_t)(kb * 4 + 3) * N + n0 + nb * 4];
            float c0[4] = {r0v.x, r0v.y, r0v.z, r0v.w};
            float c1[4] = {r1v.x, r1v.y, r1v.z, r1v.w};
            float c2[4] = {r2v.x, r2v.y, r2v.z, r2v.w};
            float c3[4] = {r3v.x, r3v.y, r3v.z, r3v.w};
            #pragma unroll
            for (int c = 0; c < 4; ++c) {
                half4 h = {(_Float16)c0[c], (_Float16)c1[c],
                           (_Float16)c2[c], (_Float16)c3[c]};
                *(half4*)&Bs[buf][nb * 4 + c][kb * 4] = h;
            }
        }
    };

    stage(0, 0);

    int rbase = blockIdx.x * 64 + wave * 16 + quad * 4;

    #pragma unroll
    for (int ct2 = 0; ct2 < 4; ++ct2) {
        __syncthreads();                       // buf[ct2&1] staged & prior reads done
        if (ct2 < 3) stage((ct2 + 1) & 1, ct2 + 1);   // overlap next stage w/ MFMA

        int cur = ct2 & 1;
        floatx4 acc[4] = {{0.f,0.f,0.f,0.f},{0.f,0.f,0.f,0.f},
                          {0.f,0.f,0.f,0.f},{0.f,0.f,0.f,0.f}};
        #pragma unroll
        for (int kk = 0; kk < 8; ++kk) {
            #pragma unroll
            for (int ct = 0; ct < 4; ++ct) {
                half8 b = *(const half8*)&Bs[cur][ct * 16 + l16][kk * 32 + quad * 8];
                acc[ct] = __builtin_amdgcn_mfma_f32_16x16x32_f16(ah[kk], b, acc[ct], 0, 0, 0);
            }
        }

        #pragma unroll
        for (int ct = 0; ct < 4; ++ct) {
            int col = n_base + ct2 * 64 + ct * 16 + l16;
            #pragma unroll
            for (int r = 0; r < 4; ++r) {
                int row = rbase + r;
                if (row < M) Z[(size_t)row * N + col] = acc[ct][r];
            }
        }
    }
}

// ---------------- Fused Sinkhorn + merged finalize (2-level election) -------
// Main body = R6's verified 53us kernel. Election: 8 group counters, EACH ON
// ITS OWN 256-B LINE (R9's fatal flaw: all on one line), + 1 super counter.
// 2048 RMWs -> 8 parallel per-line streams of 256 (~11us, hidden by block
// finish skew). Tail = R6's ILP finalize. launch_bounds stays (256,4).
#define WPB 4

__global__ __launch_bounds__(256, 4) void sinkhorn_fused(
    const float* __restrict__ Z,
    const int* __restrict__ ep, const int* __restrict__ en,
    int nE,
    float* __restrict__ cost_all,   // [MAX_ITER][2nE]
    float* __restrict__ err_part,   // [MAX_ITER][gridDim.x]
    unsigned* __restrict__ counter, // [9*CTR_STRIDE]: 8 group + 1 super, padded
    float* __restrict__ out)
{
    __shared__ float shm[WPB][32 * 36];  // union: sb=32x20, csh=32x36; tail scratch
    __shared__ float uvs[WPB][64];       // U2[0:32], V2[32:64]; then err publish

    int tid = threadIdx.x;
    int wv = tid >> 6;
    int t = tid & 63;
    int b = blockIdx.x * WPB + wv;

    int side = (b >= nE) ? 1 : 0;   // uniform per block (nE % WPB == 0)
    int e = b - side * nE;
    const int* edges = side ? en : ep;
    int nx = edges[e];
    int ny = edges[e + nE];

    int c = t & 31;
    int h = t >> 5;
    int r0 = h * 16;

    float* sb  = shm[wv];
    float* csh = shm[wv];
    float* Ul  = uvs[wv];
    float* Vl  = uvs[wv] + 32;

    // stage b point rows into LDS, padded stride 20
    {
        const float4* zb4 = (const float4*)(Z + (size_t)ny * EMB);
        float4 q0 = zb4[t * 2];
        float4 q1 = zb4[t * 2 + 1];
        float* dst = sb + (t >> 1) * 20 + (t & 1) * 8;
        ((float4*)dst)[0] = q0;
        ((float4*)dst)[1] = q1;
    }
    // own a-row in registers
    float areg[16];
    {
        const float4* za4 = (const float4*)(Z + (size_t)nx * EMB + c * SPACE_DIM);
        float4 a0 = za4[0], a1 = za4[1], a2 = za4[2], a3 = za4[3];
        areg[0]=a0.x; areg[1]=a0.y; areg[2]=a0.z; areg[3]=a0.w;
        areg[4]=a1.x; areg[5]=a1.y; areg[6]=a1.z; areg[7]=a1.w;
        areg[8]=a2.x; areg[9]=a2.y; areg[10]=a2.z; areg[11]=a2.w;
        areg[12]=a3.x; areg[13]=a3.y; areg[14]=a3.z; areg[15]=a3.w;
    }

    // Crow[jj] = -10*log2e * ||a_c - b_{r0+jj}||^2
    float Crow[16];
    #pragma unroll
    for (int jj = 0; jj < 16; ++jj) {
        const float* bp = sb + (r0 + jj) * 20;
        float s = 0.f;
        #pragma unroll
        for (int d = 0; d < SPACE_DIM; ++d) {
            float diff = areg[d] - bp[d];
            s = fmaf(diff, diff, s);
        }
        Crow[jj] = s * NEG10LOG2E;
    }
    // transpose through LDS (stride 36) to get column fragment
    #pragma unroll
    for (int g = 0; g < 4; ++g) {
        *(float4*)&csh[c * 36 + r0 + g * 4] =
            make_float4(Crow[g*4+0], Crow[g*4+1], Crow[g*4+2], Crow[g*4+3]);
    }
    float Ccol[16];
    #pragma unroll
    for (int ii = 0; ii < 16; ++ii)
        Ccol[ii] = csh[(r0 + ii) * 36 + c];

    Vl[c] = 0.f;
    float U = 0.f;
    float ccp[MAX_ITER];   // per-lane cost partials (state after iter k+1)
    float dup[MAX_ITER];   // per-lane du of iter k (duplicated across halves)

    #pragma unroll        // FULL unroll: ccp/dup indices static -> VGPRs
    for (int it = 0; it < MAX_ITER; ++it) {
        // ---- row pass ----
        float w[16];
        {
            const float4* vp = (const float4*)(Vl + r0);
            float4 v0 = vp[0], v1 = vp[1], v2 = vp[2], v3 = vp[3];
            float vv[16] = {v0.x,v0.y,v0.z,v0.w, v1.x,v1.y,v1.z,v1.w,
                            v2.x,v2.y,v2.z,v2.w, v3.x,v3.y,v3.z,v3.w};
            #pragma unroll
            for (int jj = 0; jj < 16; ++jj) w[jj] = Crow[jj] + vv[jj];
        }
        // pairwise max tree
        float m8[8];
        #pragma unroll
        for (int k = 0; k < 8; ++k) m8[k] = fmaxf(w[k], w[k + 8]);
        float m4a = fmaxf(m8[0], m8[4]), m4b = fmaxf(m8[1], m8[5]);
        float m4c = fmaxf(m8[2], m8[6]), m4d = fmaxf(m8[3], m8[7]);
        float mx = fmaxf(fmaxf(m4a, m4b), fmaxf(m4c, m4d));
        mx = fmaxf(mx, __shfl_xor(mx, 32));

        float ex[16];
        #pragma unroll
        for (int jj = 0; jj < 16; ++jj) ex[jj] = __builtin_amdgcn_exp2f(w[jj] - mx);
        // pairwise sum trees for sm and pc
        float s8[8], p8[8];
        #pragma unroll
        for (int k = 0; k < 8; ++k) {
            s8[k] = ex[k] + ex[k + 8];
            p8[k] = fmaf(ex[k], Crow[k], ex[k + 8] * Crow[k + 8]);
        }
        float sm = ((s8[0]+s8[4]) + (s8[1]+s8[5])) + ((s8[2]+s8[6]) + (s8[3]+s8[7]));
        float pc = ((p8[0]+p8[4]) + (p8[1]+p8[5])) + ((p8[2]+p8[6]) + (p8[3]+p8[7]));
        sm += __shfl_xor(sm, 32);

        // per-lane cost partial of state after `it` iterations (pre-update U)
        if (it > 0) ccp[it - 1] = __builtin_amdgcn_exp2f(U + mx) * pc;

        float Un = LOGMU2 - (mx + __builtin_amdgcn_logf(sm));
        dup[it] = fabsf(Un - U);   // identical in both halves
        U = Un;
        Ul[c] = U;

        // ---- col pass ----
        float wc[16];
        {
            const float4* up = (const float4*)(Ul + r0);
            float4 u0 = up[0], u1 = up[1], u2 = up[2], u3 = up[3];
            float uu[16] = {u0.x,u0.y,u0.z,u0.w, u1.x,u1.y,u1.z,u1.w,
                            u2.x,u2.y,u2.z,u2.w, u3.x,u3.y,u3.z,u3.w};
            #pragma unroll
            for (int ii = 0; ii < 16; ++ii) wc[ii] = Ccol[ii] + uu[ii];
        }
        float n8[8];
        #pragma unroll
        for (int k = 0; k < 8; ++k) n8[k] = fmaxf(wc[k], wc[k + 8]);
        float n4a = fmaxf(n8[0], n8[4]), n4b = fmaxf(n8[1], n8[5]);
        float n4c = fmaxf(n8[2], n8[6]), n4d = fmaxf(n8[3], n8[7]);
        float mx2 = fmaxf(fmaxf(n4a, n4b), fmaxf(n4c, n4d));
        mx2 = fmaxf(mx2, __shfl_xor(mx2, 32));

        float e2[16];
        #pragma unroll
        for (int ii = 0; ii < 16; ++ii) e2[ii] = __builtin_amdgcn_exp2f(wc[ii] - mx2);
        float t8[8];
        #pragma unroll
        for (int k = 0; k < 8; ++k) t8[k] = e2[k] + e2[k + 8];
        float sm2 = ((t8[0]+t8[4]) + (t8[1]+t8[5])) + ((t8[2]+t8[6]) + (t8[3]+t8[7]));
        sm2 += __shfl_xor(sm2, 32);
        float Vn = LOGMU2 - (mx2 + __builtin_amdgcn_logf(sm2));
        Vl[c] = Vn;
    }

    // final-state cost partial -> ccp[MAX_ITER-1]
    {
        const float4* vp = (const float4*)(Vl + r0);
        float4 v0 = vp[0], v1 = vp[1], v2 = vp[2], v3 = vp[3];
        float vv[16] = {v0.x,v0.y,v0.z,v0.w, v1.x,v1.y,v1.z,v1.w,
                        v2.x,v2.y,v2.z,v2.w, v3.x,v3.y,v3.z,v3.w};
        float cc = 0.f;
        #pragma unroll
        for (int jj = 0; jj < 16; ++jj)
            cc = fmaf(__builtin_amdgcn_exp2f(U + Crow[jj] + vv[jj]), Crow[jj], cc);
        ccp[MAX_ITER - 1] = cc;
    }

    // post-loop: 20 independent butterfly chains, latencies overlap
    #pragma unroll
    for (int m = 1; m < 32; m <<= 1) {
        #pragma unroll
        for (int k = 0; k < MAX_ITER; ++k) {
            dup[k] += __shfl_xor(dup[k], m);
            ccp[k] += __shfl_xor(ccp[k], m);
        }
    }
    #pragma unroll
    for (int k = 0; k < MAX_ITER; ++k) ccp[k] += __shfl_xor(ccp[k], 32);

    if (t == 0) {
        #pragma unroll
        for (int k = 0; k < MAX_ITER; ++k)
            cost_all[(size_t)k * (2 * nE) + b] = -EPS_LN2 * ccp[k];
        // publish this wave's err values for the block-combine
        #pragma unroll
        for (int k = 0; k < MAX_ITER; ++k) uvs[wv][k] = dup[k];
    }
    __syncthreads();

    // block-combine err across the 4 waves -> 10 plain f32 stores, no atomics
    if (tid < MAX_ITER) {
        float s4 = uvs[0][tid] + uvs[1][tid] + uvs[2][tid] + uvs[3][tid];
        err_part[(size_t)tid * gridDim.x + blockIdx.x] = EPS_LN2 * s4;
    }

    // ============== 2-level completion election + merged finalize ==========
    // Scratch overlays shm[0] (dead): em_s[96..115], isl[128], loss[200..203]
    float* sred = &shm[0][0];
    float* em_s = sred + 96;
    int*   isl  = (int*)(sred + 128);

    __syncthreads();   // all waves' global stores issued before the fence
    if (tid == 0) {
        __threadfence();                      // release our stores
        int g = (int)(blockIdx.x >> 8);       // 8 groups of 256 blocks
        int last = 0;
        unsigned o1 = __hip_atomic_fetch_add(&counter[g * CTR_STRIDE], 1u,
                          __ATOMIC_ACQ_REL, __HIP_MEMORY_SCOPE_AGENT);
        if (o1 == 255u) {
            unsigned o2 = __hip_atomic_fetch_add(&counter[8 * CTR_STRIDE], 1u,
                              __ATOMIC_ACQ_REL, __HIP_MEMORY_SCOPE_AGENT);
            last = (o2 == 7u);
        }
        *isl = last;
    }
    __syncthreads();
    if (!*isl) return;
    __threadfence();   // acquire side for all threads of the last block

    int nB = (int)gridDim.x;   // 2048

    // ---- Phase A: err row sums (R6 finalize, ILP 8-deep) ----
    for (int r = wv; r < MAX_ITER; r += 4) {
        const float4* p4 = (const float4*)(err_part + (size_t)r * nB);
        float4 v0 = p4[t       ], v1 = p4[t +  64], v2 = p4[t + 128], v3 = p4[t + 192];
        float4 v4 = p4[t + 256], v5 = p4[t + 320], v6 = p4[t + 384], v7 = p4[t + 448];
        float ps = ((v0.x+v0.y)+(v0.z+v0.w)) + ((v1.x+v1.y)+(v1.z+v1.w))
                 + ((v2.x+v2.y)+(v2.z+v2.w)) + ((v3.x+v3.y)+(v3.z+v3.w));
        float ns = ((v4.x+v4.y)+(v4.z+v4.w)) + ((v5.x+v5.y)+(v5.z+v5.w))
                 + ((v6.x+v6.y)+(v6.z+v6.w)) + ((v7.x+v7.y)+(v7.z+v7.w));
        #pragma unroll
        for (int m = 1; m < 64; m <<= 1) {
            ps += __shfl_xor(ps, m);
            ns += __shfl_xor(ns, m);
        }
        if (t == 0) {
            em_s[r] = ps / (float)nE;
            em_s[MAX_ITER + r] = ns / (float)nE;
        }
    }
    __syncthreads();

    int Tp = MAX_ITER, Tn = MAX_ITER;
    for (int i = 0; i < MAX_ITER; ++i)
        if (em_s[i] < THRESH) { Tp = i + 1; break; }
    for (int i = 0; i < MAX_ITER; ++i)
        if (em_s[MAX_ITER + i] < THRESH) { Tn = i + 1; break; }

    // ---- Phase B: final loss (R6 finalize, 8 loads in flight) ----
    const float4* cp4 = (const float4*)(cost_all + (size_t)(Tp - 1) * (2 * nE));
    const float4* cn4 = (const float4*)(cost_all + (size_t)(Tn - 1) * (2 * nE) + nE);
    float4 p0 = cp4[tid      ], p1 = cp4[tid + 256],
           p2 = cp4[tid + 512], p3 = cp4[tid + 768];
    float4 n0 = cn4[tid      ], n1 = cn4[tid + 256],
           n2 = cn4[tid + 512], n3 = cn4[tid + 768];
    float aP = 0.f;
    aP = fmaf(p0.x,p0.x,aP); aP = fmaf(p0.y,p0.y,aP);
    aP = fmaf(p0.z,p0.z,aP); aP = fmaf(p0.w,p0.w,aP);
    aP = fmaf(p1.x,p1.x,aP); aP = fmaf(p1.y,p1.y,aP);
    aP = fmaf(p1.z,p1.z,aP); aP = fmaf(p1.w,p1.w,aP);
    aP = fmaf(p2.x,p2.x,aP); aP = fmaf(p2.y,p2.y,aP);
    aP = fmaf(p2.z,p2.z,aP); aP = fmaf(p2.w,p2.w,aP);
    aP = fmaf(p3.x,p3.x,aP); aP = fmaf(p3.y,p3.y,aP);
    aP = fmaf(p3.z,p3.z,aP); aP = fmaf(p3.w,p3.w,aP);
    float aN = 0.f;
    aN += expf(-n0.x) + expf(-n0.y) + expf(-n0.z) + expf(-n0.w);
    aN += expf(-n1.x) + expf(-n1.y) + expf(-n1.z) + expf(-n1.w);
    aN += expf(-n2.x) + expf(-n2.y) + expf(-n2.z) + expf(-n2.w);
    aN += expf(-n3.x) + expf(-n3.y) + expf(-n3.z) + expf(-n3.w);
    float acc = aP + aN;
    #pragma unroll
    for (int m = 1; m < 64; m <<= 1) acc += __shfl_xor(acc, m);
    if (t == 0) sred[200 + wv] = acc;
    __syncthreads();
    if (tid == 0)
        out[0] = ((sred[200] + sred[201]) + (sred[202] + sred[203])) / (float)nE;
}

extern "C" void kernel_launch(void* const* d_in, const int* in_sizes, int n_in,
                              void* d_out, int out_size, void* d_ws, size_t ws_size,
                              hipStream_t stream)
{
    const float* X = (const float*)d_in[0];
    const float* W = (const float*)d_in[1];
    const int* ep = (const int*)d_in[2];
    const int* en = (const int*)d_in[3];
    float* out = (float*)d_out;

    int K = in_sizes[1] / EMB;     // 256
    int M = in_sizes[0] / K;       // 10000
    int nE = in_sizes[2] / 2;      // 4096

    float* ws = (float*)d_ws;
    float* Z = ws;                                          // M*EMB f32
    float* cost_all = Z + (size_t)M * EMB;                  // MAX_ITER*2nE f32
    float* err_part = cost_all + (size_t)MAX_ITER * 2 * nE; // MAX_ITER*2048 f32
    unsigned* counter = (unsigned*)(err_part + (size_t)MAX_ITER * 2048); // 9*64 u32

    dim3 gg((M + 63) / 64, 2);
    gemm_fused<<<gg, 256, 0, stream>>>(X, W, Z, M, K, EMB, counter);

    int nblk = (2 * nE) / WPB;   // 2048
    sinkhorn_fused<<<nblk, 64 * WPB, 0, stream>>>(Z, ep, en, nE, cost_all,
                                                  err_part, counter, out);
}

// Round 11
// 133.077 us; speedup vs baseline: 1.5726x; 1.5688x over previous
//
#include <hip/hip_runtime.h>
#include <hip/hip_bf16.h>
#include <math.h>

#define N_POINTS 32
#define SPACE_DIM 16
#define EMB 512
#define THRESH 0.1f
#define MAX_ITER 10
#define KDIM 256   // K fixed by the problem (feat=256)

// log2-domain constants
#define NEG10LOG2E -14.42695040888963f   // -10*log2(e): C -> Crow2
#define EPS_LN2     0.0693147180559945f  // eps*ln2
#define LOGMU2     -4.99999953834f       // log2(1/32 + 1e-8)

typedef _Float16 half8 __attribute__((ext_vector_type(8)));
typedef _Float16 half4 __attribute__((ext_vector_type(4)));
typedef float floatx4 __attribute__((ext_vector_type(4)));

#define BSTRIDE 264   // halves; 528 B rows -> b128-aligned, 2-way max (free)

// ---------------- GEMM v2: Z = X @ W, N-tile=256, X-in-reg, dbuf W ---------
// R7-verified. Single-kernel completion protocols are PERMANENTLY ruled out:
// per-block agent-scope release (threadfence -> buffer_wbl2) serializes
// device-wide at ~100cy; 2048 blocks = ~80us regardless of counter layout
// (R5/R9/R10 all measured it). Launch boundaries are cheaper.
__global__ __launch_bounds__(256) void gemm_fused(
    const float* __restrict__ X, const float* __restrict__ W,
    float* __restrict__ Z, int M, int K, int N)
{
    (void)K;  // == KDIM by problem construction

    __shared__ _Float16 Bs[2][64][BSTRIDE];   // 2 x 33.8 KB

    int t = threadIdx.x;
    int wave = t >> 6;
    int lane = t & 63;
    int quad = lane >> 4;
    int l16 = lane & 15;
    int n_base = blockIdx.y * 256;

    // ---- load + convert this lane's X slice ONCE (8 kk x 8 floats) ----
    int mrow = blockIdx.x * 64 + wave * 16 + l16;
    int msafe = mrow < M ? mrow : M - 1;
    const float4* xp = (const float4*)(X + (size_t)msafe * KDIM);

    half8 ah[8];
    #pragma unroll
    for (int kk = 0; kk < 8; ++kk) {
        float4 lo = xp[kk * 8 + quad * 2];
        float4 hi = xp[kk * 8 + quad * 2 + 1];
        ah[kk] = (half8){(_Float16)lo.x, (_Float16)lo.y, (_Float16)lo.z, (_Float16)lo.w,
                         (_Float16)hi.x, (_Float16)hi.y, (_Float16)hi.z, (_Float16)hi.w};
    }

    // ---- W subtile staging: [256k x 64n] fp32 -> Bs[buf][n][k] f16 ----
    auto stage = [&](int buf, int ct2) {
        int n0 = n_base + ct2 * 64;
        #pragma unroll
        for (int s = 0; s < 4; ++s) {
            int u = s * 256 + t;
            int nb = u & 15;          // n-group (4 cols)
            int kb = u >> 4;          // k-group (4 rows)
            float4 r0v = *(const float4*)&W[(size_t)(kb * 4 + 0) * N + n0 + nb * 4];
            float4 r1v = *(const float4*)&W[(size_t)(kb * 4 + 1) * N + n0 + nb * 4];
            float4 r2v = *(const float4*)&W[(size_t)(kb * 4 + 2) * N + n0 + nb * 4];
            float4 r3v = *(const float4*)&W[(size_t)(kb * 4 + 3) * N + n0 + nb * 4];
            float c0[4] = {r0v.x, r0v.y, r0v.z, r0v.w};
            float c1[4] = {r1v.x, r1v.y, r1v.z, r1v.w};
            float c2[4] = {r2v.x, r2v.y, r2v.z, r2v.w};
            float c3[4] = {r3v.x, r3v.y, r3v.z, r3v.w};
            #pragma unroll
            for (int c = 0; c < 4; ++c) {
                half4 h = {(_Float16)c0[c], (_Float16)c1[c],
                           (_Float16)c2[c], (_Float16)c3[c]};
                *(half4*)&Bs[buf][nb * 4 + c][kb * 4] = h;
            }
        }
    };

    stage(0, 0);

    int rbase = blockIdx.x * 64 + wave * 16 + quad * 4;

    #pragma unroll
    for (int ct2 = 0; ct2 < 4; ++ct2) {
        __syncthreads();                       // buf[ct2&1] staged & prior reads done
        if (ct2 < 3) stage((ct2 + 1) & 1, ct2 + 1);   // overlap next stage w/ MFMA

        int cur = ct2 & 1;
        floatx4 acc[4] = {{0.f,0.f,0.f,0.f},{0.f,0.f,0.f,0.f},
                          {0.f,0.f,0.f,0.f},{0.f,0.f,0.f,0.f}};
        #pragma unroll
        for (int kk = 0; kk < 8; ++kk) {
            #pragma unroll
            for (int ct = 0; ct < 4; ++ct) {
                half8 b = *(const half8*)&Bs[cur][ct * 16 + l16][kk * 32 + quad * 8];
                acc[ct] = __builtin_amdgcn_mfma_f32_16x16x32_f16(ah[kk], b, acc[ct], 0, 0, 0);
            }
        }

        #pragma unroll
        for (int ct = 0; ct < 4; ++ct) {
            int col = n_base + ct2 * 64 + ct * 16 + l16;
            #pragma unroll
            for (int r = 0; r < 4; ++r) {
                int row = rbase + r;
                if (row < M) Z[(size_t)row * N + col] = acc[ct][r];
            }
        }
    }
}

// ---------------- Fused Sinkhorn: pure compute, plain stores, NO sync -------
// (byte-identical to R6/R7's verified 53us version)
#define WPB 4

__global__ __launch_bounds__(256, 4) void sinkhorn_fused(
    const float* __restrict__ Z,
    const int* __restrict__ ep, const int* __restrict__ en,
    int nE,
    float* __restrict__ cost_all,   // [MAX_ITER][2nE]
    float* __restrict__ err_part)   // [MAX_ITER][gridDim.x]
{
    __shared__ float shm[WPB][32 * 36];  // union: sb=32x20, csh=32x36
    __shared__ float uvs[WPB][64];       // U2[0:32], V2[32:64]; then err publish

    int tid = threadIdx.x;
    int wv = tid >> 6;
    int t = tid & 63;
    int b = blockIdx.x * WPB + wv;

    int side = (b >= nE) ? 1 : 0;   // uniform per block (nE % WPB == 0)
    int e = b - side * nE;
    const int* edges = side ? en : ep;
    int nx = edges[e];
    int ny = edges[e + nE];

    int c = t & 31;
    int h = t >> 5;
    int r0 = h * 16;

    float* sb  = shm[wv];
    float* csh = shm[wv];
    float* Ul  = uvs[wv];
    float* Vl  = uvs[wv] + 32;

    // stage b point rows into LDS, padded stride 20
    {
        const float4* zb4 = (const float4*)(Z + (size_t)ny * EMB);
        float4 q0 = zb4[t * 2];
        float4 q1 = zb4[t * 2 + 1];
        float* dst = sb + (t >> 1) * 20 + (t & 1) * 8;
        ((float4*)dst)[0] = q0;
        ((float4*)dst)[1] = q1;
    }
    // own a-row in registers
    float areg[16];
    {
        const float4* za4 = (const float4*)(Z + (size_t)nx * EMB + c * SPACE_DIM);
        float4 a0 = za4[0], a1 = za4[1], a2 = za4[2], a3 = za4[3];
        areg[0]=a0.x; areg[1]=a0.y; areg[2]=a0.z; areg[3]=a0.w;
        areg[4]=a1.x; areg[5]=a1.y; areg[6]=a1.z; areg[7]=a1.w;
        areg[8]=a2.x; areg[9]=a2.y; areg[10]=a2.z; areg[11]=a2.w;
        areg[12]=a3.x; areg[13]=a3.y; areg[14]=a3.z; areg[15]=a3.w;
    }

    // Crow[jj] = -10*log2e * ||a_c - b_{r0+jj}||^2
    float Crow[16];
    #pragma unroll
    for (int jj = 0; jj < 16; ++jj) {
        const float* bp = sb + (r0 + jj) * 20;
        float s = 0.f;
        #pragma unroll
        for (int d = 0; d < SPACE_DIM; ++d) {
            float diff = areg[d] - bp[d];
            s = fmaf(diff, diff, s);
        }
        Crow[jj] = s * NEG10LOG2E;
    }
    // transpose through LDS (stride 36) to get column fragment
    #pragma unroll
    for (int g = 0; g < 4; ++g) {
        *(float4*)&csh[c * 36 + r0 + g * 4] =
            make_float4(Crow[g*4+0], Crow[g*4+1], Crow[g*4+2], Crow[g*4+3]);
    }
    float Ccol[16];
    #pragma unroll
    for (int ii = 0; ii < 16; ++ii)
        Ccol[ii] = csh[(r0 + ii) * 36 + c];

    Vl[c] = 0.f;
    float U = 0.f;
    float ccp[MAX_ITER];   // per-lane cost partials (state after iter k+1)
    float dup[MAX_ITER];   // per-lane du of iter k (duplicated across halves)

    #pragma unroll        // FULL unroll: ccp/dup indices static -> VGPRs
    for (int it = 0; it < MAX_ITER; ++it) {
        // ---- row pass ----
        float w[16];
        {
            const float4* vp = (const float4*)(Vl + r0);
            float4 v0 = vp[0], v1 = vp[1], v2 = vp[2], v3 = vp[3];
            float vv[16] = {v0.x,v0.y,v0.z,v0.w, v1.x,v1.y,v1.z,v1.w,
                            v2.x,v2.y,v2.z,v2.w, v3.x,v3.y,v3.z,v3.w};
            #pragma unroll
            for (int jj = 0; jj < 16; ++jj) w[jj] = Crow[jj] + vv[jj];
        }
        // pairwise max tree
        float m8[8];
        #pragma unroll
        for (int k = 0; k < 8; ++k) m8[k] = fmaxf(w[k], w[k + 8]);
        float m4a = fmaxf(m8[0], m8[4]), m4b = fmaxf(m8[1], m8[5]);
        float m4c = fmaxf(m8[2], m8[6]), m4d = fmaxf(m8[3], m8[7]);
        float mx = fmaxf(fmaxf(m4a, m4b), fmaxf(m4c, m4d));
        mx = fmaxf(mx, __shfl_xor(mx, 32));

        float ex[16];
        #pragma unroll
        for (int jj = 0; jj < 16; ++jj) ex[jj] = __builtin_amdgcn_exp2f(w[jj] - mx);
        // pairwise sum trees for sm and pc
        float s8[8], p8[8];
        #pragma unroll
        for (int k = 0; k < 8; ++k) {
            s8[k] = ex[k] + ex[k + 8];
            p8[k] = fmaf(ex[k], Crow[k], ex[k + 8] * Crow[k + 8]);
        }
        float sm = ((s8[0]+s8[4]) + (s8[1]+s8[5])) + ((s8[2]+s8[6]) + (s8[3]+s8[7]));
        float pc = ((p8[0]+p8[4]) + (p8[1]+p8[5])) + ((p8[2]+p8[6]) + (p8[3]+p8[7]));
        sm += __shfl_xor(sm, 32);

        // per-lane cost partial of state after `it` iterations (pre-update U)
        if (it > 0) ccp[it - 1] = __builtin_amdgcn_exp2f(U + mx) * pc;

        float Un = LOGMU2 - (mx + __builtin_amdgcn_logf(sm));
        dup[it] = fabsf(Un - U);   // identical in both halves
        U = Un;
        Ul[c] = U;

        // ---- col pass ----
        float wc[16];
        {
            const float4* up = (const float4*)(Ul + r0);
            float4 u0 = up[0], u1 = up[1], u2 = up[2], u3 = up[3];
            float uu[16] = {u0.x,u0.y,u0.z,u0.w, u1.x,u1.y,u1.z,u1.w,
                            u2.x,u2.y,u2.z,u2.w, u3.x,u3.y,u3.z,u3.w};
            #pragma unroll
            for (int ii = 0; ii < 16; ++ii) wc[ii] = Ccol[ii] + uu[ii];
        }
        float n8[8];
        #pragma unroll
        for (int k = 0; k < 8; ++k) n8[k] = fmaxf(wc[k], wc[k + 8]);
        float n4a = fmaxf(n8[0], n8[4]), n4b = fmaxf(n8[1], n8[5]);
        float n4c = fmaxf(n8[2], n8[6]), n4d = fmaxf(n8[3], n8[7]);
        float mx2 = fmaxf(fmaxf(n4a, n4b), fmaxf(n4c, n4d));
        mx2 = fmaxf(mx2, __shfl_xor(mx2, 32));

        float e2[16];
        #pragma unroll
        for (int ii = 0; ii < 16; ++ii) e2[ii] = __builtin_amdgcn_exp2f(wc[ii] - mx2);
        float t8[8];
        #pragma unroll
        for (int k = 0; k < 8; ++k) t8[k] = e2[k] + e2[k + 8];
        float sm2 = ((t8[0]+t8[4]) + (t8[1]+t8[5])) + ((t8[2]+t8[6]) + (t8[3]+t8[7]));
        sm2 += __shfl_xor(sm2, 32);
        float Vn = LOGMU2 - (mx2 + __builtin_amdgcn_logf(sm2));
        Vl[c] = Vn;
    }

    // final-state cost partial -> ccp[MAX_ITER-1]
    {
        const float4* vp = (const float4*)(Vl + r0);
        float4 v0 = vp[0], v1 = vp[1], v2 = vp[2], v3 = vp[3];
        float vv[16] = {v0.x,v0.y,v0.z,v0.w, v1.x,v1.y,v1.z,v1.w,
                        v2.x,v2.y,v2.z,v2.w, v3.x,v3.y,v3.z,v3.w};
        float cc = 0.f;
        #pragma unroll
        for (int jj = 0; jj < 16; ++jj)
            cc = fmaf(__builtin_amdgcn_exp2f(U + Crow[jj] + vv[jj]), Crow[jj], cc);
        ccp[MAX_ITER - 1] = cc;
    }

    // post-loop: 20 independent butterfly chains, latencies overlap
    #pragma unroll
    for (int m = 1; m < 32; m <<= 1) {
        #pragma unroll
        for (int k = 0; k < MAX_ITER; ++k) {
            dup[k] += __shfl_xor(dup[k], m);
            ccp[k] += __shfl_xor(ccp[k], m);
        }
    }
    #pragma unroll
    for (int k = 0; k < MAX_ITER; ++k) ccp[k] += __shfl_xor(ccp[k], 32);

    if (t == 0) {
        #pragma unroll
        for (int k = 0; k < MAX_ITER; ++k)
            cost_all[(size_t)k * (2 * nE) + b] = -EPS_LN2 * ccp[k];
        // publish this wave's err values for the block-combine
        #pragma unroll
        for (int k = 0; k < MAX_ITER; ++k) uvs[wv][k] = dup[k];
    }
    __syncthreads();

    // block-combine err across the 4 waves -> 10 plain f32 stores, no atomics
    if (tid < MAX_ITER) {
        float s4 = uvs[0][tid] + uvs[1][tid] + uvs[2][tid] + uvs[3][tid];
        err_part[(size_t)tid * gridDim.x + blockIdx.x] = EPS_LN2 * s4;
    }
}

// ---------------- finalize: 1 block, all loads explicitly in flight --------
__global__ __launch_bounds__(256) void finalize(
    const float* __restrict__ err_part,   // [MAX_ITER][nB]
    const float* __restrict__ cost_all,   // [MAX_ITER][2nE]
    float* __restrict__ out, int nE, int nB)
{
    __shared__ float em_s[2 * MAX_ITER];
    __shared__ float red[4];

    int tid = threadIdx.x;
    int wv = tid >> 6;
    int t = tid & 63;

    // ---- Phase A: err row sums; wave wv takes rows wv, wv+4, wv+8 ----
    // nB == 2048 by construction: 512 float4/row; lane t reads t + j*64.
    for (int r = wv; r < MAX_ITER; r += 4) {
        const float4* p4 = (const float4*)(err_part + (size_t)r * nB);
        float4 v0 = p4[t       ], v1 = p4[t +  64], v2 = p4[t + 128], v3 = p4[t + 192];
        float4 v4 = p4[t + 256], v5 = p4[t + 320], v6 = p4[t + 384], v7 = p4[t + 448];
        float ps = ((v0.x+v0.y)+(v0.z+v0.w)) + ((v1.x+v1.y)+(v1.z+v1.w))
                 + ((v2.x+v2.y)+(v2.z+v2.w)) + ((v3.x+v3.y)+(v3.z+v3.w));
        float ns = ((v4.x+v4.y)+(v4.z+v4.w)) + ((v5.x+v5.y)+(v5.z+v5.w))
                 + ((v6.x+v6.y)+(v6.z+v6.w)) + ((v7.x+v7.y)+(v7.z+v7.w));
        #pragma unroll
        for (int m = 1; m < 64; m <<= 1) {
            ps += __shfl_xor(ps, m);
            ns += __shfl_xor(ns, m);
        }
        if (t == 0) {
            em_s[r] = ps / (float)nE;
            em_s[MAX_ITER + r] = ns / (float)nE;
        }
    }
    __syncthreads();

    int Tp = MAX_ITER, Tn = MAX_ITER;
    for (int i = 0; i < MAX_ITER; ++i)
        if (em_s[i] < THRESH) { Tp = i + 1; break; }
    for (int i = 0; i < MAX_ITER; ++i)
        if (em_s[MAX_ITER + i] < THRESH) { Tn = i + 1; break; }

    // ---- Phase B: final loss; nE == 4096 -> 1024 float4 per side ----
    const float4* cp4 = (const float4*)(cost_all + (size_t)(Tp - 1) * (2 * nE));
    const float4* cn4 = (const float4*)(cost_all + (size_t)(Tn - 1) * (2 * nE) + nE);
    float4 p0 = cp4[tid      ], p1 = cp4[tid + 256],
           p2 = cp4[tid + 512], p3 = cp4[tid + 768];
    float4 n0 = cn4[tid      ], n1 = cn4[tid + 256],
           n2 = cn4[tid + 512], n3 = cn4[tid + 768];
    float aP = 0.f;
    aP = fmaf(p0.x,p0.x,aP); aP = fmaf(p0.y,p0.y,aP);
    aP = fmaf(p0.z,p0.z,aP); aP = fmaf(p0.w,p0.w,aP);
    aP = fmaf(p1.x,p1.x,aP); aP = fmaf(p1.y,p1.y,aP);
    aP = fmaf(p1.z,p1.z,aP); aP = fmaf(p1.w,p1.w,aP);
    aP = fmaf(p2.x,p2.x,aP); aP = fmaf(p2.y,p2.y,aP);
    aP = fmaf(p2.z,p2.z,aP); aP = fmaf(p2.w,p2.w,aP);
    aP = fmaf(p3.x,p3.x,aP); aP = fmaf(p3.y,p3.y,aP);
    aP = fmaf(p3.z,p3.z,aP); aP = fmaf(p3.w,p3.w,aP);
    float aN = 0.f;
    aN += expf(-n0.x) + expf(-n0.y) + expf(-n0.z) + expf(-n0.w);
    aN += expf(-n1.x) + expf(-n1.y) + expf(-n1.z) + expf(-n1.w);
    aN += expf(-n2.x) + expf(-n2.y) + expf(-n2.z) + expf(-n2.w);
    aN += expf(-n3.x) + expf(-n3.y) + expf(-n3.z) + expf(-n3.w);
    float acc = aP + aN;
    #pragma unroll
    for (int m = 1; m < 64; m <<= 1) acc += __shfl_xor(acc, m);
    if (t == 0) red[wv] = acc;
    __syncthreads();
    if (tid == 0)
        out[0] = ((red[0] + red[1]) + (red[2] + red[3])) / (float)nE;
}

extern "C" void kernel_launch(void* const* d_in, const int* in_sizes, int n_in,
                              void* d_out, int out_size, void* d_ws, size_t ws_size,
                              hipStream_t stream)
{
    const float* X = (const float*)d_in[0];
    const float* W = (const float*)d_in[1];
    const int* ep = (const int*)d_in[2];
    const int* en = (const int*)d_in[3];
    float* out = (float*)d_out;

    int K = in_sizes[1] / EMB;     // 256
    int M = in_sizes[0] / K;       // 10000
    int nE = in_sizes[2] / 2;      // 4096

    float* ws = (float*)d_ws;
    float* Z = ws;                                          // M*EMB f32
    float* cost_all = Z + (size_t)M * EMB;                  // MAX_ITER*2nE f32
    float* err_part = cost_all + (size_t)MAX_ITER * 2 * nE; // MAX_ITER*nB f32

    dim3 gg((M + 63) / 64, 2);
    gemm_fused<<<gg, 256, 0, stream>>>(X, W, Z, M, K, EMB);

    int nblk = (2 * nE) / WPB;   // 2048
    sinkhorn_fused<<<nblk, 64 * WPB, 0, stream>>>(Z, ep, en, nE,
                                                  cost_all, err_part);

    finalize<<<1, 256, 0, stream>>>(err_part, cost_all, out, nE, nblk);
}

// Round 12
// 130.885 us; speedup vs baseline: 1.5990x; 1.0168x over previous
//
#include <hip/hip_runtime.h>
#include <hip/hip_bf16.h>
#include <math.h>

#define N_POINTS 32
#define SPACE_DIM 16
#define EMB 512
#define THRESH 0.1f
#define MAX_ITER 10
#define KDIM 256   // K fixed by the problem (feat=256)

// log2-domain constants
#define NEG10LOG2E -14.42695040888963f   // -10*log2(e): C -> Crow2
#define EPS_LN2     0.0693147180559945f  // eps*ln2
#define LOGMU2     -4.99999953834f       // log2(1/32 + 1e-8)

typedef _Float16 half8 __attribute__((ext_vector_type(8)));
typedef _Float16 half4 __attribute__((ext_vector_type(4)));
typedef float floatx4 __attribute__((ext_vector_type(4)));

#define BSTRIDE 264   // halves; 528 B rows -> b128-aligned, 2-way max (free)

// ---------------- GEMM v3: Z = X @ W, 128-row blocks, N-tile=256 -----------
// R12 null-test: halve W re-fetch (80->40MB), halve convert work, halve block
// count vs v2. grid (79,2), 512 threads (8 waves x 16 rows). Same verified
// staging/MFMA/epilogue algebra. If total doesn't move, gemm was already
// small and the residual ~76us is pipeline-fixed overhead.
__global__ __launch_bounds__(512) void gemm_fused(
    const float* __restrict__ X, const float* __restrict__ W,
    float* __restrict__ Z, int M, int K, int N)
{
    (void)K;  // == KDIM by problem construction

    __shared__ _Float16 Bs[2][64][BSTRIDE];   // 2 x 33.8 KB

    int t = threadIdx.x;          // 0..511
    int wave = t >> 6;            // 0..7
    int lane = t & 63;
    int quad = lane >> 4;
    int l16 = lane & 15;
    int n_base = blockIdx.y * 256;

    // ---- load + convert this lane's X slice ONCE (8 kk x 8 floats) ----
    int mrow = blockIdx.x * 128 + wave * 16 + l16;
    int msafe = mrow < M ? mrow : M - 1;
    const float4* xp = (const float4*)(X + (size_t)msafe * KDIM);

    half8 ah[8];
    #pragma unroll
    for (int kk = 0; kk < 8; ++kk) {
        float4 lo = xp[kk * 8 + quad * 2];
        float4 hi = xp[kk * 8 + quad * 2 + 1];
        ah[kk] = (half8){(_Float16)lo.x, (_Float16)lo.y, (_Float16)lo.z, (_Float16)lo.w,
                         (_Float16)hi.x, (_Float16)hi.y, (_Float16)hi.z, (_Float16)hi.w};
    }

    // ---- W subtile staging: [256k x 64n] fp32 -> Bs[buf][n][k] f16 ----
    // 512 threads: 2 s-iters x 512 = 1024 u-slots = 16 nb x 64 kb (full cover)
    auto stage = [&](int buf, int ct2) {
        int n0 = n_base + ct2 * 64;
        #pragma unroll
        for (int s = 0; s < 2; ++s) {
            int u = s * 512 + t;
            int nb = u & 15;          // n-group (4 cols)
            int kb = u >> 4;          // k-group (4 rows), 0..63
            float4 r0v = *(const float4*)&W[(size_t)(kb * 4 + 0) * N + n0 + nb * 4];
            float4 r1v = *(const float4*)&W[(size_t)(kb * 4 + 1) * N + n0 + nb * 4];
            float4 r2v = *(const float4*)&W[(size_t)(kb * 4 + 2) * N + n0 + nb * 4];
            float4 r3v = *(const float4*)&W[(size_t)(kb * 4 + 3) * N + n0 + nb * 4];
            float c0[4] = {r0v.x, r0v.y, r0v.z, r0v.w};
            float c1[4] = {r1v.x, r1v.y, r1v.z, r1v.w};
            float c2[4] = {r2v.x, r2v.y, r2v.z, r2v.w};
            float c3[4] = {r3v.x, r3v.y, r3v.z, r3v.w};
            #pragma unroll
            for (int c = 0; c < 4; ++c) {
                half4 h = {(_Float16)c0[c], (_Float16)c1[c],
                           (_Float16)c2[c], (_Float16)c3[c]};
                *(half4*)&Bs[buf][nb * 4 + c][kb * 4] = h;
            }
        }
    };

    stage(0, 0);

    int rbase = blockIdx.x * 128 + wave * 16 + quad * 4;

    #pragma unroll
    for (int ct2 = 0; ct2 < 4; ++ct2) {
        __syncthreads();                       // buf[ct2&1] staged & prior reads done
        if (ct2 < 3) stage((ct2 + 1) & 1, ct2 + 1);   // overlap next stage w/ MFMA

        int cur = ct2 & 1;
        floatx4 acc[4] = {{0.f,0.f,0.f,0.f},{0.f,0.f,0.f,0.f},
                          {0.f,0.f,0.f,0.f},{0.f,0.f,0.f,0.f}};
        #pragma unroll
        for (int kk = 0; kk < 8; ++kk) {
            #pragma unroll
            for (int ct = 0; ct < 4; ++ct) {
                half8 b = *(const half8*)&Bs[cur][ct * 16 + l16][kk * 32 + quad * 8];
                acc[ct] = __builtin_amdgcn_mfma_f32_16x16x32_f16(ah[kk], b, acc[ct], 0, 0, 0);
            }
        }

        #pragma unroll
        for (int ct = 0; ct < 4; ++ct) {
            int col = n_base + ct2 * 64 + ct * 16 + l16;
            #pragma unroll
            for (int r = 0; r < 4; ++r) {
                int row = rbase + r;
                if (row < M) Z[(size_t)row * N + col] = acc[ct][r];
            }
        }
    }
}

// ---------------- Fused Sinkhorn: pure compute, plain stores, NO sync -------
// (byte-identical to R11's verified 53us version)
#define WPB 4

__global__ __launch_bounds__(256, 4) void sinkhorn_fused(
    const float* __restrict__ Z,
    const int* __restrict__ ep, const int* __restrict__ en,
    int nE,
    float* __restrict__ cost_all,   // [MAX_ITER][2nE]
    float* __restrict__ err_part)   // [MAX_ITER][gridDim.x]
{
    __shared__ float shm[WPB][32 * 36];  // union: sb=32x20, csh=32x36
    __shared__ float uvs[WPB][64];       // U2[0:32], V2[32:64]; then err publish

    int tid = threadIdx.x;
    int wv = tid >> 6;
    int t = tid & 63;
    int b = blockIdx.x * WPB + wv;

    int side = (b >= nE) ? 1 : 0;   // uniform per block (nE % WPB == 0)
    int e = b - side * nE;
    const int* edges = side ? en : ep;
    int nx = edges[e];
    int ny = edges[e + nE];

    int c = t & 31;
    int h = t >> 5;
    int r0 = h * 16;

    float* sb  = shm[wv];
    float* csh = shm[wv];
    float* Ul  = uvs[wv];
    float* Vl  = uvs[wv] + 32;

    // stage b point rows into LDS, padded stride 20
    {
        const float4* zb4 = (const float4*)(Z + (size_t)ny * EMB);
        float4 q0 = zb4[t * 2];
        float4 q1 = zb4[t * 2 + 1];
        float* dst = sb + (t >> 1) * 20 + (t & 1) * 8;
        ((float4*)dst)[0] = q0;
        ((float4*)dst)[1] = q1;
    }
    // own a-row in registers
    float areg[16];
    {
        const float4* za4 = (const float4*)(Z + (size_t)nx * EMB + c * SPACE_DIM);
        float4 a0 = za4[0], a1 = za4[1], a2 = za4[2], a3 = za4[3];
        areg[0]=a0.x; areg[1]=a0.y; areg[2]=a0.z; areg[3]=a0.w;
        areg[4]=a1.x; areg[5]=a1.y; areg[6]=a1.z; areg[7]=a1.w;
        areg[8]=a2.x; areg[9]=a2.y; areg[10]=a2.z; areg[11]=a2.w;
        areg[12]=a3.x; areg[13]=a3.y; areg[14]=a3.z; areg[15]=a3.w;
    }

    // Crow[jj] = -10*log2e * ||a_c - b_{r0+jj}||^2
    float Crow[16];
    #pragma unroll
    for (int jj = 0; jj < 16; ++jj) {
        const float* bp = sb + (r0 + jj) * 20;
        float s = 0.f;
        #pragma unroll
        for (int d = 0; d < SPACE_DIM; ++d) {
            float diff = areg[d] - bp[d];
            s = fmaf(diff, diff, s);
        }
        Crow[jj] = s * NEG10LOG2E;
    }
    // transpose through LDS (stride 36) to get column fragment
    #pragma unroll
    for (int g = 0; g < 4; ++g) {
        *(float4*)&csh[c * 36 + r0 + g * 4] =
            make_float4(Crow[g*4+0], Crow[g*4+1], Crow[g*4+2], Crow[g*4+3]);
    }
    float Ccol[16];
    #pragma unroll
    for (int ii = 0; ii < 16; ++ii)
        Ccol[ii] = csh[(r0 + ii) * 36 + c];

    Vl[c] = 0.f;
    float U = 0.f;
    float ccp[MAX_ITER];   // per-lane cost partials (state after iter k+1)
    float dup[MAX_ITER];   // per-lane du of iter k (duplicated across halves)

    #pragma unroll        // FULL unroll: ccp/dup indices static -> VGPRs
    for (int it = 0; it < MAX_ITER; ++it) {
        // ---- row pass ----
        float w[16];
        {
            const float4* vp = (const float4*)(Vl + r0);
            float4 v0 = vp[0], v1 = vp[1], v2 = vp[2], v3 = vp[3];
            float vv[16] = {v0.x,v0.y,v0.z,v0.w, v1.x,v1.y,v1.z,v1.w,
                            v2.x,v2.y,v2.z,v2.w, v3.x,v3.y,v3.z,v3.w};
            #pragma unroll
            for (int jj = 0; jj < 16; ++jj) w[jj] = Crow[jj] + vv[jj];
        }
        // pairwise max tree
        float m8[8];
        #pragma unroll
        for (int k = 0; k < 8; ++k) m8[k] = fmaxf(w[k], w[k + 8]);
        float m4a = fmaxf(m8[0], m8[4]), m4b = fmaxf(m8[1], m8[5]);
        float m4c = fmaxf(m8[2], m8[6]), m4d = fmaxf(m8[3], m8[7]);
        float mx = fmaxf(fmaxf(m4a, m4b), fmaxf(m4c, m4d));
        mx = fmaxf(mx, __shfl_xor(mx, 32));

        float ex[16];
        #pragma unroll
        for (int jj = 0; jj < 16; ++jj) ex[jj] = __builtin_amdgcn_exp2f(w[jj] - mx);
        // pairwise sum trees for sm and pc
        float s8[8], p8[8];
        #pragma unroll
        for (int k = 0; k < 8; ++k) {
            s8[k] = ex[k] + ex[k + 8];
            p8[k] = fmaf(ex[k], Crow[k], ex[k + 8] * Crow[k + 8]);
        }
        float sm = ((s8[0]+s8[4]) + (s8[1]+s8[5])) + ((s8[2]+s8[6]) + (s8[3]+s8[7]));
        float pc = ((p8[0]+p8[4]) + (p8[1]+p8[5])) + ((p8[2]+p8[6]) + (p8[3]+p8[7]));
        sm += __shfl_xor(sm, 32);

        // per-lane cost partial of state after `it` iterations (pre-update U)
        if (it > 0) ccp[it - 1] = __builtin_amdgcn_exp2f(U + mx) * pc;

        float Un = LOGMU2 - (mx + __builtin_amdgcn_logf(sm));
        dup[it] = fabsf(Un - U);   // identical in both halves
        U = Un;
        Ul[c] = U;

        // ---- col pass ----
        float wc[16];
        {
            const float4* up = (const float4*)(Ul + r0);
            float4 u0 = up[0], u1 = up[1], u2 = up[2], u3 = up[3];
            float uu[16] = {u0.x,u0.y,u0.z,u0.w, u1.x,u1.y,u1.z,u1.w,
                            u2.x,u2.y,u2.z,u2.w, u3.x,u3.y,u3.z,u3.w};
            #pragma unroll
            for (int ii = 0; ii < 16; ++ii) wc[ii] = Ccol[ii] + uu[ii];
        }
        float n8[8];
        #pragma unroll
        for (int k = 0; k < 8; ++k) n8[k] = fmaxf(wc[k], wc[k + 8]);
        float n4a = fmaxf(n8[0], n8[4]), n4b = fmaxf(n8[1], n8[5]);
        float n4c = fmaxf(n8[2], n8[6]), n4d = fmaxf(n8[3], n8[7]);
        float mx2 = fmaxf(fmaxf(n4a, n4b), fmaxf(n4c, n4d));
        mx2 = fmaxf(mx2, __shfl_xor(mx2, 32));

        float e2[16];
        #pragma unroll
        for (int ii = 0; ii < 16; ++ii) e2[ii] = __builtin_amdgcn_exp2f(wc[ii] - mx2);
        float t8[8];
        #pragma unroll
        for (int k = 0; k < 8; ++k) t8[k] = e2[k] + e2[k + 8];
        float sm2 = ((t8[0]+t8[4]) + (t8[1]+t8[5])) + ((t8[2]+t8[6]) + (t8[3]+t8[7]));
        sm2 += __shfl_xor(sm2, 32);
        float Vn = LOGMU2 - (mx2 + __builtin_amdgcn_logf(sm2));
        Vl[c] = Vn;
    }

    // final-state cost partial -> ccp[MAX_ITER-1]
    {
        const float4* vp = (const float4*)(Vl + r0);
        float4 v0 = vp[0], v1 = vp[1], v2 = vp[2], v3 = vp[3];
        float vv[16] = {v0.x,v0.y,v0.z,v0.w, v1.x,v1.y,v1.z,v1.w,
                        v2.x,v2.y,v2.z,v2.w, v3.x,v3.y,v3.z,v3.w};
        float cc = 0.f;
        #pragma unroll
        for (int jj = 0; jj < 16; ++jj)
            cc = fmaf(__builtin_amdgcn_exp2f(U + Crow[jj] + vv[jj]), Crow[jj], cc);
        ccp[MAX_ITER - 1] = cc;
    }

    // post-loop: 20 independent butterfly chains, latencies overlap
    #pragma unroll
    for (int m = 1; m < 32; m <<= 1) {
        #pragma unroll
        for (int k = 0; k < MAX_ITER; ++k) {
            dup[k] += __shfl_xor(dup[k], m);
            ccp[k] += __shfl_xor(ccp[k], m);
        }
    }
    #pragma unroll
    for (int k = 0; k < MAX_ITER; ++k) ccp[k] += __shfl_xor(ccp[k], 32);

    if (t == 0) {
        #pragma unroll
        for (int k = 0; k < MAX_ITER; ++k)
            cost_all[(size_t)k * (2 * nE) + b] = -EPS_LN2 * ccp[k];
        // publish this wave's err values for the block-combine
        #pragma unroll
        for (int k = 0; k < MAX_ITER; ++k) uvs[wv][k] = dup[k];
    }
    __syncthreads();

    // block-combine err across the 4 waves -> 10 plain f32 stores, no atomics
    if (tid < MAX_ITER) {
        float s4 = uvs[0][tid] + uvs[1][tid] + uvs[2][tid] + uvs[3][tid];
        err_part[(size_t)tid * gridDim.x + blockIdx.x] = EPS_LN2 * s4;
    }
}

// ---------------- finalize: 1 block, all loads explicitly in flight --------
__global__ __launch_bounds__(256) void finalize(
    const float* __restrict__ err_part,   // [MAX_ITER][nB]
    const float* __restrict__ cost_all,   // [MAX_ITER][2nE]
    float* __restrict__ out, int nE, int nB)
{
    __shared__ float em_s[2 * MAX_ITER];
    __shared__ float red[4];

    int tid = threadIdx.x;
    int wv = tid >> 6;
    int t = tid & 63;

    // ---- Phase A: err row sums; wave wv takes rows wv, wv+4, wv+8 ----
    // nB == 2048 by construction: 512 float4/row; lane t reads t + j*64.
    for (int r = wv; r < MAX_ITER; r += 4) {
        const float4* p4 = (const float4*)(err_part + (size_t)r * nB);
        float4 v0 = p4[t       ], v1 = p4[t +  64], v2 = p4[t + 128], v3 = p4[t + 192];
        float4 v4 = p4[t + 256], v5 = p4[t + 320], v6 = p4[t + 384], v7 = p4[t + 448];
        float ps = ((v0.x+v0.y)+(v0.z+v0.w)) + ((v1.x+v1.y)+(v1.z+v1.w))
                 + ((v2.x+v2.y)+(v2.z+v2.w)) + ((v3.x+v3.y)+(v3.z+v3.w));
        float ns = ((v4.x+v4.y)+(v4.z+v4.w)) + ((v5.x+v5.y)+(v5.z+v5.w))
                 + ((v6.x+v6.y)+(v6.z+v6.w)) + ((v7.x+v7.y)+(v7.z+v7.w));
        #pragma unroll
        for (int m = 1; m < 64; m <<= 1) {
            ps += __shfl_xor(ps, m);
            ns += __shfl_xor(ns, m);
        }
        if (t == 0) {
            em_s[r] = ps / (float)nE;
            em_s[MAX_ITER + r] = ns / (float)nE;
        }
    }
    __syncthreads();

    int Tp = MAX_ITER, Tn = MAX_ITER;
    for (int i = 0; i < MAX_ITER; ++i)
        if (em_s[i] < THRESH) { Tp = i + 1; break; }
    for (int i = 0; i < MAX_ITER; ++i)
        if (em_s[MAX_ITER + i] < THRESH) { Tn = i + 1; break; }

    // ---- Phase B: final loss; nE == 4096 -> 1024 float4 per side ----
    const float4* cp4 = (const float4*)(cost_all + (size_t)(Tp - 1) * (2 * nE));
    const float4* cn4 = (const float4*)(cost_all + (size_t)(Tn - 1) * (2 * nE) + nE);
    float4 p0 = cp4[tid      ], p1 = cp4[tid + 256],
           p2 = cp4[tid + 512], p3 = cp4[tid + 768];
    float4 n0 = cn4[tid      ], n1 = cn4[tid + 256],
           n2 = cn4[tid + 512], n3 = cn4[tid + 768];
    float aP = 0.f;
    aP = fmaf(p0.x,p0.x,aP); aP = fmaf(p0.y,p0.y,aP);
    aP = fmaf(p0.z,p0.z,aP); aP = fmaf(p0.w,p0.w,aP);
    aP = fmaf(p1.x,p1.x,aP); aP = fmaf(p1.y,p1.y,aP);
    aP = fmaf(p1.z,p1.z,aP); aP = fmaf(p1.w,p1.w,aP);
    aP = fmaf(p2.x,p2.x,aP); aP = fmaf(p2.y,p2.y,aP);
    aP = fmaf(p2.z,p2.z,aP); aP = fmaf(p2.w,p2.w,aP);
    aP = fmaf(p3.x,p3.x,aP); aP = fmaf(p3.y,p3.y,aP);
    aP = fmaf(p3.z,p3.z,aP); aP = fmaf(p3.w,p3.w,aP);
    float aN = 0.f;
    aN += expf(-n0.x) + expf(-n0.y) + expf(-n0.z) + expf(-n0.w);
    aN += expf(-n1.x) + expf(-n1.y) + expf(-n1.z) + expf(-n1.w);
    aN += expf(-n2.x) + expf(-n2.y) + expf(-n2.z) + expf(-n2.w);
    aN += expf(-n3.x) + expf(-n3.y) + expf(-n3.z) + expf(-n3.w);
    float acc = aP + aN;
    #pragma unroll
    for (int m = 1; m < 64; m <<= 1) acc += __shfl_xor(acc, m);
    if (t == 0) red[wv] = acc;
    __syncthreads();
    if (tid == 0)
        out[0] = ((red[0] + red[1]) + (red[2] + red[3])) / (float)nE;
}

extern "C" void kernel_launch(void* const* d_in, const int* in_sizes, int n_in,
                              void* d_out, int out_size, void* d_ws, size_t ws_size,
                              hipStream_t stream)
{
    const float* X = (const float*)d_in[0];
    const float* W = (const float*)d_in[1];
    const int* ep = (const int*)d_in[2];
    const int* en = (const int*)d_in[3];
    float* out = (float*)d_out;

    int K = in_sizes[1] / EMB;     // 256
    int M = in_sizes[0] / K;       // 10000
    int nE = in_sizes[2] / 2;      // 4096

    float* ws = (float*)d_ws;
    float* Z = ws;                                          // M*EMB f32
    float* cost_all = Z + (size_t)M * EMB;                  // MAX_ITER*2nE f32
    float* err_part = cost_all + (size_t)MAX_ITER * 2 * nE; // MAX_ITER*nB f32

    dim3 gg((M + 127) / 128, 2);
    gemm_fused<<<gg, 512, 0, stream>>>(X, W, Z, M, K, EMB);

    int nblk = (2 * nE) / WPB;   // 2048
    sinkhorn_fused<<<nblk, 64 * WPB, 0, stream>>>(Z, ep, en, nE,
                                                  cost_all, err_part);

    finalize<<<1, 256, 0, stream>>>(err_part, cost_all, out, nE, nblk);
}